// Round 4
// baseline (152.880 us; speedup 1.0000x reference)
//
#include <hip/hip_runtime.h>

#define NUM_CLASSES 5
#define BATCH 4
#define NPB (64 * 256 * 256)            // voxels per batch = 4,194,304
#define VEC_PER_BATCH (NPB / 4)         // int4 vectors per batch = 1,048,576
#define THREADS 256
#define VECS 16                         // int4 per thread per input (64 voxels)
#define CHUNK 8                         // int4 per load burst (32 voxels -> 6-bit safe)
#define BLOCKS_X (VEC_PER_BATCH / (THREADS * VECS))   // 256 per batch
#define TOTAL_BLOCKS (BLOCKS_X * BATCH)               // 1024
#define SLOTS 15                        // 5 pred, 5 targ, 5 inter
#define PSTRIDE 16                      // padded per-block partial stride

// d_ws: partial[block][PSTRIDE] uints, block = b*BLOCKS_X + bx. No zero-init
// needed: every slot that dice_final_kernel reads is written unconditionally.

__global__ __launch_bounds__(THREADS, 4) void dice_count_kernel(
    const int* __restrict__ pred, const int* __restrict__ targ,
    unsigned int* __restrict__ partial) {
  const int b = blockIdx.y;
  const int4* __restrict__ p4 = (const int4*)(pred + (long long)b * NPB);
  const int4* __restrict__ t4 = (const int4*)(targ + (long long)b * NPB);

  const int base = blockIdx.x * (THREADS * VECS) + threadIdx.x;

  // Packed per-lane counters: class c in bits [6c, 6c+6); per-chunk count <= 32.
  unsigned accP[2] = {0, 0}, accT[2] = {0, 0}, accI[2] = {0, 0};

#pragma unroll
  for (int h = 0; h < 2; ++h) {
    int4 pv[CHUNK], tv[CHUNK];
    // Burst: 16 independent 16B loads in flight before any use.
#pragma unroll
    for (int k = 0; k < CHUNK; ++k) {
      const int idx = base + (h * CHUNK + k) * THREADS;
      pv[k] = p4[idx];
      tv[k] = t4[idx];
    }
    unsigned aP = 0, aT = 0, aI = 0;
#define ACC_ELEM(PE, TE)                               \
    {                                                  \
      const unsigned op = 1u << (6u * (unsigned)(PE)); \
      aP += op;                                        \
      aT += 1u << (6u * (unsigned)(TE));               \
      aI += ((PE) == (TE)) ? op : 0u;                  \
    }
#pragma unroll
    for (int k = 0; k < CHUNK; ++k) {
      ACC_ELEM(pv[k].x, tv[k].x)
      ACC_ELEM(pv[k].y, tv[k].y)
      ACC_ELEM(pv[k].z, tv[k].z)
      ACC_ELEM(pv[k].w, tv[k].w)
    }
    accP[h] = aP; accT[h] = aT; accI[h] = aI;
  }

  // Unpack 6-bit fields of both chunks -> 16-bit pairs (per-field <= 64, fits).
#define UNPACK(A, R01, R23, R4)                                          \
  unsigned R01 = ((A[0] & 63u) + (A[1] & 63u)) |                         \
                 ((((A[0] >> 6) & 63u) + ((A[1] >> 6) & 63u)) << 16);    \
  unsigned R23 = (((A[0] >> 12) & 63u) + ((A[1] >> 12) & 63u)) |         \
                 ((((A[0] >> 18) & 63u) + ((A[1] >> 18) & 63u)) << 16);  \
  unsigned R4 = ((A[0] >> 24) & 63u) + ((A[1] >> 24) & 63u);
  UNPACK(accP, p01, p23, p4r)
  UNPACK(accT, t01, t23, t4r)
  UNPACK(accI, i01, i23, i4r)

  // 64-lane butterfly; 16-bit fields hold <= 64*64 = 4096, no overflow.
#pragma unroll
  for (int off = 32; off >= 1; off >>= 1) {
    p01 += (unsigned)__shfl_xor((int)p01, off);
    p23 += (unsigned)__shfl_xor((int)p23, off);
    p4r += (unsigned)__shfl_xor((int)p4r, off);
    t01 += (unsigned)__shfl_xor((int)t01, off);
    t23 += (unsigned)__shfl_xor((int)t23, off);
    t4r += (unsigned)__shfl_xor((int)t4r, off);
    i01 += (unsigned)__shfl_xor((int)i01, off);
    i23 += (unsigned)__shfl_xor((int)i23, off);
    i4r += (unsigned)__shfl_xor((int)i4r, off);
  }

  __shared__ unsigned int s[SLOTS];
  if (threadIdx.x < SLOTS) s[threadIdx.x] = 0;
  __syncthreads();

  if ((threadIdx.x & 63) == 0) {
    atomicAdd(&s[0], p01 & 0xFFFFu);
    atomicAdd(&s[1], p01 >> 16);
    atomicAdd(&s[2], p23 & 0xFFFFu);
    atomicAdd(&s[3], p23 >> 16);
    atomicAdd(&s[4], p4r);
    atomicAdd(&s[5], t01 & 0xFFFFu);
    atomicAdd(&s[6], t01 >> 16);
    atomicAdd(&s[7], t23 & 0xFFFFu);
    atomicAdd(&s[8], t23 >> 16);
    atomicAdd(&s[9], t4r);
    atomicAdd(&s[10], i01 & 0xFFFFu);
    atomicAdd(&s[11], i01 >> 16);
    atomicAdd(&s[12], i23 & 0xFFFFu);
    atomicAdd(&s[13], i23 >> 16);
    atomicAdd(&s[14], i4r);
  }
  __syncthreads();

  if (threadIdx.x < SLOTS)
    partial[(b * BLOCKS_X + blockIdx.x) * PSTRIDE + threadIdx.x] = s[threadIdx.x];
}

__global__ void dice_final_kernel(const unsigned int* __restrict__ partial,
                                  float* __restrict__ out) {
  __shared__ unsigned int tot[BATCH * SLOTS];
  const int t = threadIdx.x;
  if (t < BATCH * SLOTS) {
    const int slot = t % SLOTS;
    const int bb = t / SLOTS;
    unsigned int sum = 0;
    for (int j = 0; j < BLOCKS_X; ++j)
      sum += partial[(bb * BLOCKS_X + j) * PSTRIDE + slot];
    tot[t] = sum;
  }
  __syncthreads();
  if (t < NUM_CLASSES) {
    float acc = 0.0f;
#pragma unroll
    for (int bb = 0; bb < BATCH; ++bb) {
      const float ps = (float)tot[bb * SLOTS + t];
      const float ts = (float)tot[bb * SLOTS + 5 + t];
      const float is = (float)tot[bb * SLOTS + 10 + t];
      float num = 2.0f * is;
      float den = ps + ts;
      if (den == 0.0f) { num = 1.0f; den = 1.0f; }
      acc += num / den;
    }
    out[t] = acc * (1.0f / BATCH);
  }
}

extern "C" void kernel_launch(void* const* d_in, const int* in_sizes, int n_in,
                              void* d_out, int out_size, void* d_ws, size_t ws_size,
                              hipStream_t stream) {
  const int* pred = (const int*)d_in[0];
  const int* targ = (const int*)d_in[1];
  float* out = (float*)d_out;
  unsigned int* partial = (unsigned int*)d_ws;

  dim3 grid(BLOCKS_X, BATCH);
  dice_count_kernel<<<grid, THREADS, 0, stream>>>(pred, targ, partial);
  dice_final_kernel<<<1, 64, 0, stream>>>(partial, out);
}

// Round 5
// 147.757 us; speedup vs baseline: 1.0347x; 1.0347x over previous
//
#include <hip/hip_runtime.h>

#define NUM_CLASSES 5
#define BATCH 4
#define NPB (64 * 256 * 256)            // voxels per batch = 4,194,304
#define VEC_PER_BATCH (NPB / 4)         // int4 vectors per batch = 1,048,576
#define THREADS 256
#define VECS 16                         // int4 per thread per input (64 voxels)
#define CHUNK 8                         // int4 per forced load burst (32 voxels -> 6-bit safe)
#define BLOCKS_X (VEC_PER_BATCH / (THREADS * VECS))   // 256 per batch
#define SLOTS 15                        // 5 pred, 5 targ, 5 inter
#define PSTRIDE 16                      // padded per-block partial stride

// d_ws: partial[block][PSTRIDE] uints, block = b*BLOCKS_X + bx. No zero-init
// needed: every slot dice_final_kernel reads is written unconditionally.

__global__ __launch_bounds__(THREADS, 4) void dice_count_kernel(
    const int* __restrict__ pred, const int* __restrict__ targ,
    unsigned int* __restrict__ partial) {
  const int b = blockIdx.y;
  const int4* __restrict__ p4 = (const int4*)(pred + (long long)b * NPB);
  const int4* __restrict__ t4 = (const int4*)(targ + (long long)b * NPB);

  const int base = blockIdx.x * (THREADS * VECS) + threadIdx.x;

  // Packed per-lane counters: class c in bits [6c, 6c+6); per-chunk count <= 32.
  unsigned accP[2] = {0, 0}, accT[2] = {0, 0}, accI[2] = {0, 0};

#pragma unroll
  for (int h = 0; h < 2; ++h) {
    int4 pv[CHUNK], tv[CHUNK];
    // Burst: 16 independent 16B loads. sched_barrier(0) below forbids the
    // scheduler from sinking these into their uses -> all 16 stay in flight
    // (64 data VGPRs live). This is the round-5 mechanism under test.
#pragma unroll
    for (int k = 0; k < CHUNK; ++k) {
      const int idx = base + (h * CHUNK + k) * THREADS;
      pv[k] = p4[idx];
      tv[k] = t4[idx];
    }
    __builtin_amdgcn_sched_barrier(0);
    unsigned aP = 0, aT = 0, aI = 0;
#define ACC_ELEM(PE, TE)                               \
    {                                                  \
      const unsigned op = 1u << (6u * (unsigned)(PE)); \
      aP += op;                                        \
      aT += 1u << (6u * (unsigned)(TE));               \
      aI += ((PE) == (TE)) ? op : 0u;                  \
    }
#pragma unroll
    for (int k = 0; k < CHUNK; ++k) {
      ACC_ELEM(pv[k].x, tv[k].x)
      ACC_ELEM(pv[k].y, tv[k].y)
      ACC_ELEM(pv[k].z, tv[k].z)
      ACC_ELEM(pv[k].w, tv[k].w)
    }
    accP[h] = aP; accT[h] = aT; accI[h] = aI;
  }

  // Unpack 6-bit fields of both chunks -> 16-bit pairs (per-field <= 64, fits).
#define UNPACK(A, R01, R23, R4)                                          \
  unsigned R01 = ((A[0] & 63u) + (A[1] & 63u)) |                         \
                 ((((A[0] >> 6) & 63u) + ((A[1] >> 6) & 63u)) << 16);    \
  unsigned R23 = (((A[0] >> 12) & 63u) + ((A[1] >> 12) & 63u)) |         \
                 ((((A[0] >> 18) & 63u) + ((A[1] >> 18) & 63u)) << 16);  \
  unsigned R4 = ((A[0] >> 24) & 63u) + ((A[1] >> 24) & 63u);
  UNPACK(accP, p01, p23, p4r)
  UNPACK(accT, t01, t23, t4r)
  UNPACK(accI, i01, i23, i4r)

  // 64-lane butterfly; 16-bit fields hold <= 64*64 = 4096, no overflow.
#pragma unroll
  for (int off = 32; off >= 1; off >>= 1) {
    p01 += (unsigned)__shfl_xor((int)p01, off);
    p23 += (unsigned)__shfl_xor((int)p23, off);
    p4r += (unsigned)__shfl_xor((int)p4r, off);
    t01 += (unsigned)__shfl_xor((int)t01, off);
    t23 += (unsigned)__shfl_xor((int)t23, off);
    t4r += (unsigned)__shfl_xor((int)t4r, off);
    i01 += (unsigned)__shfl_xor((int)i01, off);
    i23 += (unsigned)__shfl_xor((int)i23, off);
    i4r += (unsigned)__shfl_xor((int)i4r, off);
  }

  __shared__ unsigned int s[SLOTS];
  if (threadIdx.x < SLOTS) s[threadIdx.x] = 0;
  __syncthreads();

  if ((threadIdx.x & 63) == 0) {
    atomicAdd(&s[0], p01 & 0xFFFFu);
    atomicAdd(&s[1], p01 >> 16);
    atomicAdd(&s[2], p23 & 0xFFFFu);
    atomicAdd(&s[3], p23 >> 16);
    atomicAdd(&s[4], p4r);
    atomicAdd(&s[5], t01 & 0xFFFFu);
    atomicAdd(&s[6], t01 >> 16);
    atomicAdd(&s[7], t23 & 0xFFFFu);
    atomicAdd(&s[8], t23 >> 16);
    atomicAdd(&s[9], t4r);
    atomicAdd(&s[10], i01 & 0xFFFFu);
    atomicAdd(&s[11], i01 >> 16);
    atomicAdd(&s[12], i23 & 0xFFFFu);
    atomicAdd(&s[13], i23 >> 16);
    atomicAdd(&s[14], i4r);
  }
  __syncthreads();

  if (threadIdx.x < SLOTS)
    partial[(b * BLOCKS_X + blockIdx.x) * PSTRIDE + threadIdx.x] = s[threadIdx.x];
}

__global__ __launch_bounds__(256) void dice_final_kernel(
    const unsigned int* __restrict__ partial, float* __restrict__ out) {
  // 240 active threads: t = (bb*SLOTS + slot)*4 + q; q splits the 256 blocks
  // of one batch into quarters for parallel latency hiding.
  __shared__ unsigned int red[BATCH * SLOTS][4];
  const int t = threadIdx.x;
  if (t < BATCH * SLOTS * 4) {
    const int q = t & 3;
    const int s = (t >> 2) % SLOTS;
    const int bb = (t >> 2) / SLOTS;
    unsigned int sum = 0;
    for (int j = q * (BLOCKS_X / 4); j < (q + 1) * (BLOCKS_X / 4); ++j)
      sum += partial[(bb * BLOCKS_X + j) * PSTRIDE + s];
    red[(t >> 2)][q] = sum;
  }
  __syncthreads();
  if (t < NUM_CLASSES) {
    float acc = 0.0f;
#pragma unroll
    for (int bb = 0; bb < BATCH; ++bb) {
      const int ip = bb * SLOTS + t;
      const int it = bb * SLOTS + 5 + t;
      const int ii = bb * SLOTS + 10 + t;
      const float ps = (float)(red[ip][0] + red[ip][1] + red[ip][2] + red[ip][3]);
      const float ts = (float)(red[it][0] + red[it][1] + red[it][2] + red[it][3]);
      const float is = (float)(red[ii][0] + red[ii][1] + red[ii][2] + red[ii][3]);
      float num = 2.0f * is;
      float den = ps + ts;
      if (den == 0.0f) { num = 1.0f; den = 1.0f; }
      acc += num / den;
    }
    out[t] = acc * (1.0f / BATCH);
  }
}

extern "C" void kernel_launch(void* const* d_in, const int* in_sizes, int n_in,
                              void* d_out, int out_size, void* d_ws, size_t ws_size,
                              hipStream_t stream) {
  const int* pred = (const int*)d_in[0];
  const int* targ = (const int*)d_in[1];
  float* out = (float*)d_out;
  unsigned int* partial = (unsigned int*)d_ws;

  dim3 grid(BLOCKS_X, BATCH);
  dice_count_kernel<<<grid, THREADS, 0, stream>>>(pred, targ, partial);
  dice_final_kernel<<<1, 256, 0, stream>>>(partial, out);
}